// Round 7
// baseline (4539.397 us; speedup 1.0000x reference)
//
#include <hip/hip_runtime.h>
#include <stdint.h>

#define B_ 256
#define T_ 512
#define F_ 128
#define U_ 256
#define H_ 64
#define G4U (4 * U_)

typedef __attribute__((ext_vector_type(8))) short short8;
typedef __attribute__((ext_vector_type(4))) float f32x4;
typedef unsigned long long ull;

// LDS-only barrier: NO vmcnt drain (publish/seq stores stay in flight).
#define BARRIER_LDS() asm volatile("s_waitcnt lgkmcnt(0)\ns_barrier" ::: "memory")

__device__ __forceinline__ uint16_t f2bf(float f) {
  uint32_t u = __builtin_bit_cast(uint32_t, f);
  u += 0x7fffu + ((u >> 16) & 1u);
  return (uint16_t)(u >> 16);
}
__device__ __forceinline__ float sigm(float z) {
  return 1.0f / (1.0f + __expf(-z));
}
__device__ __forceinline__ ull ald(const ull* p) {
  return __hip_atomic_load(p, __ATOMIC_RELAXED, __HIP_MEMORY_SCOPE_AGENT);
}

// ---------------------------------------------------------------------------
// Persistent LSTM, pairwise topology, register-budget-safe (R6 lesson:
// VGPR hard cap = 256; weights-in-VGPR must be <= ~200/wave).
// 32 WGs x 512 threads (8 waves). Group bg in [0,16): 16 batch rows.
// Member m in {0,1} owns units [m*128,(m+1)*128) = 512 gate-cols.
// Per wave: rec B-frags in VGPR (4 coltiles x 8kt = 128 regs); x-projection
// B-frags pre-packed in LDS (128 KB, conflict-free b128 reads).
// Wave wv owns units [wv*16, wv*16+16): lane il = one unit, all 4 gates in
// acc[q] -> gates fully in registers, cst[4]/lane.
// Exchange: tagged 8B words {h[2p][u],h[2p+1][u] | tag t+1}, 2-slot parity,
// single MALL trip; poll = 16 B/thread contiguous, self-paced retry.
// Rec-MFMA split own-half/peer-half: own half + x-MFMA overlap poll wait.
// ---------------------------------------------------------------------------
__global__ __launch_bounds__(512, 2) void lstm_kernel(
    const float* __restrict__ x, const float* __restrict__ kern,
    const float* __restrict__ rker, const float* __restrict__ bias,
    uint16_t* __restrict__ seq, ull* __restrict__ hbuf)
{
  const int tid  = threadIdx.x;
  const int lane = tid & 63;
  const int wv   = tid >> 6;          // 0..7
  const int il   = lane & 15;
  const int rg   = lane >> 4;         // 0..3
  const int bg   = blockIdx.x & 15;
  const int m    = blockIdx.x >> 4;   // member 0/1

  // LDS: x A-frags (4 KB) + h A-frags 2-parity (16 KB) + kern B-frags (128 KB)
  __shared__ __align__(16) uint16_t x_stage[4][64][8];        // 4 KB
  __shared__ __align__(16) uint16_t h_stage[2][8][64][8];     // 16 KB
  __shared__ __align__(16) uint16_t kern_lds[8192 * 8];       // 128 KB: [ct*4+kt][lane][8]

  // ---- rec B-frags in VGPR: wf[q][kt], cols gcol = q*256 + m*128 + wv*16+il
  short8 wf[4][8];
  float  bias_r[4];
  #pragma unroll
  for (int q = 0; q < 4; ++q) {
    const int gcol = q * U_ + m * 128 + wv * 16 + il;
    bias_r[q] = bias[gcol];
    #pragma unroll
    for (int kt = 0; kt < 8; ++kt) {
      short8 v;
      #pragma unroll
      for (int j = 0; j < 8; ++j)
        v[j] = (short)f2bf(rker[(size_t)(kt * 32 + rg * 8 + j) * G4U + gcol]);
      wf[q][kt] = v;
    }
  }

  // ---- stage kern B-frags into LDS: slot = (ct*4+kt)*64+lane, ct = q*8+w
  for (int s = 0; s < 16; ++s) {
    const int slot = tid + s * 512;
    const int ln = slot & 63, kt = (slot >> 6) & 3, ct = slot >> 8;
    const int col = (ct >> 3) * U_ + m * 128 + (ct & 7) * 16 + (ln & 15);
    const int kb  = kt * 32 + (ln >> 4) * 8;
    short8 v;
    #pragma unroll
    for (int j = 0; j < 8; ++j)
      v[j] = (short)f2bf(kern[(size_t)(kb + j) * G4U + col]);
    *(short8*)&kern_lds[(size_t)slot * 8] = v;
  }

  // ---- x staging role: thread owns 4 consecutive u16 of x_stage flat
  const int xkt = tid >> 7;                 // 0..3
  const int xln = (tid >> 1) & 63;
  const int xj0 = (tid & 1) * 4;
  const int xrow = xln & 15;
  const int xk0  = xkt * 32 + (xln >> 4) * 8 + xj0;

  // own unit constants
  const int Ua  = m * 128 + wv * 16 + il;   // global unit
  const int kta = Ua >> 5, ga = ((Ua & 31) >> 3) * 16, posa = Ua & 7;

  ull* const pub_s  = hbuf + (size_t)(bg * 2 + m) * 2048;
  const ull* const pub_p  = hbuf + (size_t)(bg * 2 + (m ^ 1)) * 2048;

  float cst[4];
  #pragma unroll
  for (int j = 0; j < 4; ++j) cst[j] = 0.f;

  // ---- stage x for t=0 ----
  float xp[4];
  {
    const float* p = x + ((size_t)(bg * 16 + xrow) * T_ + 0) * F_ + xk0;
    #pragma unroll
    for (int j = 0; j < 4; ++j) xp[j] = p[j];
    uint16_t* d = (uint16_t*)x_stage + tid * 4;
    #pragma unroll
    for (int j = 0; j < 4; ++j) d[j] = f2bf(xp[j]);
  }
  __syncthreads();

  for (int t = 0; t < T_; ++t) {
    // (A) issue peer poll loads (slot (t-1)&1), 16B/thread contiguous
    const ull* pp = pub_p + (size_t)((t - 1) & 1) * 1024 + tid * 2;
    ull pv0, pv1;
    if (t > 0) { pv0 = ald(pp); pv1 = ald(pp + 1); }
    __builtin_amdgcn_sched_barrier(0);   // keep issue above the MFMA block
    // x prefetch for t+1
    {
      const int tn = (t + 1 < T_) ? t + 1 : t;
      const float* p = x + ((size_t)(bg * 16 + xrow) * T_ + tn) * F_ + xk0;
      #pragma unroll
      for (int j = 0; j < 4; ++j) xp[j] = p[j];
    }
    // (B) acc = bias + x_t @ kernel  (B-frags from LDS)
    f32x4 acc[4];
    #pragma unroll
    for (int q = 0; q < 4; ++q)
      acc[q] = (f32x4){bias_r[q], bias_r[q], bias_r[q], bias_r[q]};
    #pragma unroll
    for (int kt = 0; kt < 4; ++kt) {
      short8 a = *(const short8*)&x_stage[kt][lane][0];
      #pragma unroll
      for (int q = 0; q < 4; ++q) {
        short8 b = *(const short8*)&kern_lds[(size_t)(((q * 8 + wv) * 4 + kt) * 64 + lane) * 8];
        acc[q] = __builtin_amdgcn_mfma_f32_16x16x32_bf16(a, b, acc[q], 0, 0, 0);
      }
    }
    if (t > 0) {
      // (C) OWN-half rec (units of this member; h written locally last step)
      const int p_ = (t - 1) & 1;
      #pragma unroll
      for (int k2 = 0; k2 < 4; ++k2) {
        const int kt = m * 4 + k2;
        short8 a = *(const short8*)&h_stage[p_][kt][lane][0];
        #pragma unroll
        for (int q = 0; q < 4; ++q)
          acc[q] = __builtin_amdgcn_mfma_f32_16x16x32_bf16(a, wf[q][kt], acc[q], 0, 0, 0);
      }
      // (D) poll retry (self-paced by load latency), then unpack peer half
      const uint32_t expt = (uint32_t)t;
      while (((uint32_t)(pv0 >> 32) != expt) | ((uint32_t)(pv1 >> 32) != expt)) {
        pv0 = ald(pp); pv1 = ald(pp + 1);
      }
      const int u_loc = tid >> 2;
      const int U  = (m ^ 1) * 128 + u_loc;
      const int kt = U >> 5, g = ((U & 31) >> 3) * 16, pos = U & 7;
      const int rb = (tid & 3) * 4;
      h_stage[p_][kt][g + rb + 0][pos] = (uint16_t)pv0;
      h_stage[p_][kt][g + rb + 1][pos] = (uint16_t)(pv0 >> 16);
      h_stage[p_][kt][g + rb + 2][pos] = (uint16_t)pv1;
      h_stage[p_][kt][g + rb + 3][pos] = (uint16_t)(pv1 >> 16);
    }
    BARRIER_LDS();   // (BAR-M) peer h_stage ready; x_stage reads done
    if (t > 0) {
      // (E) PEER-half rec
      const int p_ = (t - 1) & 1;
      #pragma unroll
      for (int k2 = 0; k2 < 4; ++k2) {
        const int kt = (m ^ 1) * 4 + k2;
        short8 a = *(const short8*)&h_stage[p_][kt][lane][0];
        #pragma unroll
        for (int q = 0; q < 4; ++q)
          acc[q] = __builtin_amdgcn_mfma_f32_16x16x32_bf16(a, wf[q][kt], acc[q], 0, 0, 0);
      }
    }
    // stage x_{t+1} (x_stage reads all completed before BAR-M)
    {
      uint16_t* d = (uint16_t*)x_stage + tid * 4;
      #pragma unroll
      for (int j = 0; j < 4; ++j) d[j] = f2bf(xp[j]);
    }
    // (F) gates in registers + publish + own-h -> LDS + seq
    {
      uint16_t b16[4];
      #pragma unroll
      for (int j = 0; j < 4; ++j) {
        const float zi = acc[0][j], zf = acc[1][j];
        const float zg = acc[2][j], zo = acc[3][j];
        const float ii = sigm(zi), ff = sigm(zf);
        const float gg = zg * sigm(zg), oo = sigm(zo);
        const float c  = ff * cst[j] + ii * gg;
        cst[j] = c;
        b16[j] = f2bf(oo * (c * sigm(c)));
      }
      const int s2 = t & 1;
      ull* pw = pub_s + (size_t)s2 * 1024 + (size_t)(wv * 16 + il) * 8 + rg * 2;
      const ull tg = (ull)(uint32_t)(t + 1) << 32;
      __hip_atomic_store(pw,     (ull)((uint32_t)b16[0] | ((uint32_t)b16[1] << 16)) | tg,
                         __ATOMIC_RELAXED, __HIP_MEMORY_SCOPE_AGENT);
      __hip_atomic_store(pw + 1, (ull)((uint32_t)b16[2] | ((uint32_t)b16[3] << 16)) | tg,
                         __ATOMIC_RELAXED, __HIP_MEMORY_SCOPE_AGENT);
      #pragma unroll
      for (int j = 0; j < 4; ++j) {
        h_stage[s2][kta][ga + rg * 4 + j][posa] = b16[j];
        seq[((size_t)(bg * 16 + rg * 4 + j) * T_ + t) * U_ + Ua] = b16[j];
      }
    }
    BARRIER_LDS();   // (BAR-E) x_stage + own-h visible for next step
  }
}

// ---------------------------------------------------------------------------
// Head GEMM: partials[g][b][h] = seq[b, g-chunk] @ w_out[g-chunk, h]
// ---------------------------------------------------------------------------
__global__ __launch_bounds__(256, 1) void head_kernel(
    const uint16_t* __restrict__ seq, const float* __restrict__ w_out,
    float* __restrict__ partials)
{
  const int g    = blockIdx.x;
  const int tid  = threadIdx.x;
  const int lane = tid & 63;
  const int wv   = tid >> 6;

  f32x4 acc[4][4];
  #pragma unroll
  for (int i = 0; i < 4; ++i)
    #pragma unroll
    for (int c = 0; c < 4; ++c) acc[i][c] = (f32x4){0.f, 0.f, 0.f, 0.f};

  for (int ks = 0; ks < 64; ++ks) {
    const int krow = g * 2048 + ks * 32 + (lane >> 4) * 8;
    short8 bf[4];
    #pragma unroll
    for (int c = 0; c < 4; ++c) {
      short8 v;
      #pragma unroll
      for (int j = 0; j < 8; ++j)
        v[j] = (short)f2bf(w_out[(size_t)(krow + j) * H_ + c * 16 + (lane & 15)]);
      bf[c] = v;
    }
    #pragma unroll
    for (int i = 0; i < 4; ++i) {
      const int b = (wv * 4 + i) * 16 + (lane & 15);
      short8 a = *(const short8*)(seq + (size_t)b * (T_ * U_) + krow);
      #pragma unroll
      for (int c = 0; c < 4; ++c)
        acc[i][c] = __builtin_amdgcn_mfma_f32_16x16x32_bf16(a, bf[c], acc[i][c], 0, 0, 0);
    }
  }
  #pragma unroll
  for (int i = 0; i < 4; ++i)
    #pragma unroll
    for (int c = 0; c < 4; ++c)
      #pragma unroll
      for (int r = 0; r < 4; ++r) {
        const int b = wv * 64 + i * 16 + (lane >> 4) * 4 + r;
        partials[((size_t)g * B_ + b) * H_ + c * 16 + (lane & 15)] = acc[i][c][r];
      }
}

__global__ void reduce_kernel(const float* __restrict__ partials,
                              const float* __restrict__ b_out,
                              float* __restrict__ out)
{
  const int i = blockIdx.x * 256 + threadIdx.x;   // b*64 + h
  float s = b_out[i & (H_ - 1)];
  #pragma unroll 8
  for (int g = 0; g < 64; ++g) s += partials[(size_t)g * (B_ * H_) + i];
  out[i] = s;
}

// ---------------------------------------------------------------------------
extern "C" void kernel_launch(void* const* d_in, const int* in_sizes, int n_in,
                              void* d_out, int out_size, void* d_ws, size_t ws_size,
                              hipStream_t stream) {
  (void)in_sizes; (void)n_in; (void)out_size; (void)ws_size;
  const float* x     = (const float*)d_in[0];
  const float* kern  = (const float*)d_in[1];
  const float* rker  = (const float*)d_in[2];
  const float* bias  = (const float*)d_in[3];
  const float* w_out = (const float*)d_in[4];
  const float* b_out = (const float*)d_in[5];
  float* out = (float*)d_out;

  char* ws = (char*)d_ws;
  const size_t seq_bytes  = (size_t)B_ * T_ * U_ * 2;            // 64 MB
  const size_t hbuf_bytes = (size_t)32 * 2048 * 8;               // 512 KB tagged
  uint16_t* seq      = (uint16_t*)ws;
  ull*      hbuf     = (ull*)(ws + seq_bytes);
  float*    partials = (float*)(ws + seq_bytes + hbuf_bytes);    // 4 MB

  // per-launch re-init: stale tags from a previous graph replay would false-
  // match (tags cycle 1..512) -> zero the tagged buffer every launch.
  hipMemsetAsync(hbuf, 0, hbuf_bytes, stream);

  lstm_kernel<<<32, 512, 0, stream>>>(x, kern, rker, bias, seq, hbuf);
  head_kernel<<<64, 256, 0, stream>>>(seq, w_out, partials);
  reduce_kernel<<<64, 256, 0, stream>>>(partials, b_out, out);
}

// Round 8
// 1286.487 us; speedup vs baseline: 3.5285x; 3.5285x over previous
//
#include <hip/hip_runtime.h>
#include <stdint.h>

#define B_ 256
#define T_ 512
#define F_ 128
#define U_ 256
#define H_ 64
#define G4U (4 * U_)

typedef __attribute__((ext_vector_type(8))) short short8;
typedef __attribute__((ext_vector_type(4))) float f32x4;
typedef unsigned long long ull;

// LDS-only barrier: NO vmcnt drain (publish/seq stores stay in flight).
#define BARRIER_LDS() asm volatile("s_waitcnt lgkmcnt(0)\ns_barrier" ::: "memory")

__device__ __forceinline__ uint16_t f2bf(float f) {
  uint32_t u = __builtin_bit_cast(uint32_t, f);
  u += 0x7fffu + ((u >> 16) & 1u);
  return (uint16_t)(u >> 16);
}
__device__ __forceinline__ float sigm(float z) {
  return 1.0f / (1.0f + __expf(-z));
}
__device__ __forceinline__ ull ald(const ull* p) {
  return __hip_atomic_load(p, __ATOMIC_RELAXED, __HIP_MEMORY_SCOPE_AGENT);
}

// ---------------------------------------------------------------------------
// Persistent LSTM, pairwise topology. R7 lesson (rule #20): wf[q][m*4+k2]
// with runtime m sent the whole weight array to scratch (VGPR_Count=88).
// Fix: wf slot order is position-independent -- kk<4 = OWN k-tiles
// (real kt = m*4+kk), kk>=4 = PEER (real kt = (m^1)*4+kk-4). Runtime m only
// appears in global-load addresses (init) and LDS A-operand addresses.
// Every wf[][] access in MFMA loops is compile-time constant.
//
// 32 WGs x 512 threads (8 waves). Group bg in [0,16): 16 batch rows.
// Member m in {0,1} owns units [m*128,(m+1)*128) = 512 gate-cols.
// rec B-frags in VGPR (128 regs/wave); x-proj B-frags in LDS (128 KB).
// Wave wv owns units [wv*16,wv*16+16): lane il = one unit, all 4 gates in
// acc[q]; gates fully in registers, cst[4]/lane.
// Exchange: tagged 8B words, 2-slot parity, one-way publish; poll =
// 16B/thread contiguous, self-paced retry. Pair on same XCD (blockIdx
// round-robin heuristic; correctness is placement-independent).
// ---------------------------------------------------------------------------
__global__ __launch_bounds__(512, 2) void lstm_kernel(
    const float* __restrict__ x, const float* __restrict__ kern,
    const float* __restrict__ rker, const float* __restrict__ bias,
    uint16_t* __restrict__ seq, ull* __restrict__ hbuf)
{
  const int tid  = threadIdx.x;
  const int lane = tid & 63;
  const int wv   = tid >> 6;          // 0..7
  const int il   = lane & 15;
  const int rg   = lane >> 4;         // 0..3
  const int bg   = blockIdx.x & 15;
  const int m    = blockIdx.x >> 4;   // member 0/1

  // LDS: x A-frags (4 KB) + h A-frags 2-parity (16 KB) + kern B-frags (128 KB)
  __shared__ __align__(16) uint16_t x_stage[4][64][8];        // 4 KB
  __shared__ __align__(16) uint16_t h_stage[2][8][64][8];     // 16 KB
  __shared__ __align__(16) uint16_t kern_lds[8192 * 8];       // 128 KB: [ct*4+kt][lane][8]

  // ---- rec B-frags in VGPR, position-independent slots:
  // wf[q][kk]: kk 0..3 = OWN k-tiles (kt = m*4+kk), 4..7 = PEER k-tiles.
  short8 wf[4][8];
  float  bias_r[4];
  #pragma unroll
  for (int q = 0; q < 4; ++q) {
    const int gcol = q * U_ + m * 128 + wv * 16 + il;
    bias_r[q] = bias[gcol];
    #pragma unroll
    for (int kk = 0; kk < 8; ++kk) {
      const int ktg = ((kk & 4) ? (m ^ 1) : m) * 4 + (kk & 3);   // real k-tile
      short8 v;
      #pragma unroll
      for (int j = 0; j < 8; ++j)
        v[j] = (short)f2bf(rker[(size_t)(ktg * 32 + rg * 8 + j) * G4U + gcol]);
      wf[q][kk] = v;
    }
  }

  // ---- stage kern B-frags into LDS: slot = (ct*4+kt)*64+lane, ct = q*8+w
  for (int s = 0; s < 16; ++s) {
    const int slot = tid + s * 512;
    const int ln = slot & 63, kt = (slot >> 6) & 3, ct = slot >> 8;
    const int col = (ct >> 3) * U_ + m * 128 + (ct & 7) * 16 + (ln & 15);
    const int kb  = kt * 32 + (ln >> 4) * 8;
    short8 v;
    #pragma unroll
    for (int j = 0; j < 8; ++j)
      v[j] = (short)f2bf(kern[(size_t)(kb + j) * G4U + col]);
    *(short8*)&kern_lds[(size_t)slot * 8] = v;
  }

  // ---- x staging role: thread owns 4 consecutive u16 of x_stage flat
  const int xkt = tid >> 7;                 // 0..3
  const int xln = (tid >> 1) & 63;
  const int xj0 = (tid & 1) * 4;
  const int xrow = xln & 15;
  const int xk0  = xkt * 32 + (xln >> 4) * 8 + xj0;

  // own unit constants
  const int Ua  = m * 128 + wv * 16 + il;   // global unit
  const int kta = Ua >> 5, ga = ((Ua & 31) >> 3) * 16, posa = Ua & 7;

  ull* const pub_s  = hbuf + (size_t)(bg * 2 + m) * 2048;
  const ull* const pub_p  = hbuf + (size_t)(bg * 2 + (m ^ 1)) * 2048;

  float cst[4];
  #pragma unroll
  for (int j = 0; j < 4; ++j) cst[j] = 0.f;

  // ---- stage x for t=0 ----
  float xp[4];
  {
    const float* p = x + ((size_t)(bg * 16 + xrow) * T_ + 0) * F_ + xk0;
    #pragma unroll
    for (int j = 0; j < 4; ++j) xp[j] = p[j];
    uint16_t* d = (uint16_t*)x_stage + tid * 4;
    #pragma unroll
    for (int j = 0; j < 4; ++j) d[j] = f2bf(xp[j]);
  }
  __syncthreads();

  for (int t = 0; t < T_; ++t) {
    // (A) issue peer poll loads (slot (t-1)&1), 16B/thread contiguous
    const ull* pp = pub_p + (size_t)((t - 1) & 1) * 1024 + tid * 2;
    ull pv0, pv1;
    if (t > 0) { pv0 = ald(pp); pv1 = ald(pp + 1); }
    __builtin_amdgcn_sched_barrier(0);   // keep issue above the MFMA block
    // x prefetch for t+1
    {
      const int tn = (t + 1 < T_) ? t + 1 : t;
      const float* p = x + ((size_t)(bg * 16 + xrow) * T_ + tn) * F_ + xk0;
      #pragma unroll
      for (int j = 0; j < 4; ++j) xp[j] = p[j];
    }
    // (B) acc = bias + x_t @ kernel  (B-frags from LDS)
    f32x4 acc[4];
    #pragma unroll
    for (int q = 0; q < 4; ++q)
      acc[q] = (f32x4){bias_r[q], bias_r[q], bias_r[q], bias_r[q]};
    #pragma unroll
    for (int kt = 0; kt < 4; ++kt) {
      short8 a = *(const short8*)&x_stage[kt][lane][0];
      #pragma unroll
      for (int q = 0; q < 4; ++q) {
        short8 b = *(const short8*)&kern_lds[(size_t)(((q * 8 + wv) * 4 + kt) * 64 + lane) * 8];
        acc[q] = __builtin_amdgcn_mfma_f32_16x16x32_bf16(a, b, acc[q], 0, 0, 0);
      }
    }
    if (t > 0) {
      // (C) OWN-half rec: A from h_stage[p_][m*4+kk] (runtime LDS addr OK),
      // B from wf[q][kk] -- STATIC index, stays in VGPRs.
      const int p_ = (t - 1) & 1;
      #pragma unroll
      for (int kk = 0; kk < 4; ++kk) {
        short8 a = *(const short8*)&h_stage[p_][m * 4 + kk][lane][0];
        #pragma unroll
        for (int q = 0; q < 4; ++q)
          acc[q] = __builtin_amdgcn_mfma_f32_16x16x32_bf16(a, wf[q][kk], acc[q], 0, 0, 0);
      }
      // (D) poll retry (self-paced by load latency), then unpack peer half
      const uint32_t expt = (uint32_t)t;
      while (((uint32_t)(pv0 >> 32) != expt) | ((uint32_t)(pv1 >> 32) != expt)) {
        pv0 = ald(pp); pv1 = ald(pp + 1);
      }
      const int u_loc = tid >> 2;
      const int U  = (m ^ 1) * 128 + u_loc;
      const int kt = U >> 5, g = ((U & 31) >> 3) * 16, pos = U & 7;
      const int rb = (tid & 3) * 4;
      h_stage[p_][kt][g + rb + 0][pos] = (uint16_t)pv0;
      h_stage[p_][kt][g + rb + 1][pos] = (uint16_t)(pv0 >> 16);
      h_stage[p_][kt][g + rb + 2][pos] = (uint16_t)pv1;
      h_stage[p_][kt][g + rb + 3][pos] = (uint16_t)(pv1 >> 16);
    }
    BARRIER_LDS();   // (BAR-M) peer h_stage ready; x_stage reads done
    if (t > 0) {
      // (E) PEER-half rec: A from h_stage[p_][(m^1)*4+kk], B wf[q][4+kk] (static)
      const int p_ = (t - 1) & 1;
      #pragma unroll
      for (int kk = 0; kk < 4; ++kk) {
        short8 a = *(const short8*)&h_stage[p_][(m ^ 1) * 4 + kk][lane][0];
        #pragma unroll
        for (int q = 0; q < 4; ++q)
          acc[q] = __builtin_amdgcn_mfma_f32_16x16x32_bf16(a, wf[q][4 + kk], acc[q], 0, 0, 0);
      }
    }
    // stage x_{t+1} (x_stage reads all completed before BAR-M)
    {
      uint16_t* d = (uint16_t*)x_stage + tid * 4;
      #pragma unroll
      for (int j = 0; j < 4; ++j) d[j] = f2bf(xp[j]);
    }
    // (F) gates in registers + publish + own-h -> LDS + seq
    {
      uint16_t b16[4];
      #pragma unroll
      for (int j = 0; j < 4; ++j) {
        const float zi = acc[0][j], zf = acc[1][j];
        const float zg = acc[2][j], zo = acc[3][j];
        const float ii = sigm(zi), ff = sigm(zf);
        const float gg = zg * sigm(zg), oo = sigm(zo);
        const float c  = ff * cst[j] + ii * gg;
        cst[j] = c;
        b16[j] = f2bf(oo * (c * sigm(c)));
      }
      const int s2 = t & 1;
      ull* pw = pub_s + (size_t)s2 * 1024 + (size_t)(wv * 16 + il) * 8 + rg * 2;
      const ull tg = (ull)(uint32_t)(t + 1) << 32;
      __hip_atomic_store(pw,     (ull)((uint32_t)b16[0] | ((uint32_t)b16[1] << 16)) | tg,
                         __ATOMIC_RELAXED, __HIP_MEMORY_SCOPE_AGENT);
      __hip_atomic_store(pw + 1, (ull)((uint32_t)b16[2] | ((uint32_t)b16[3] << 16)) | tg,
                         __ATOMIC_RELAXED, __HIP_MEMORY_SCOPE_AGENT);
      #pragma unroll
      for (int j = 0; j < 4; ++j) {
        h_stage[s2][kta][ga + rg * 4 + j][posa] = b16[j];
        seq[((size_t)(bg * 16 + rg * 4 + j) * T_ + t) * U_ + Ua] = b16[j];
      }
    }
    BARRIER_LDS();   // (BAR-E) x_stage + own-h visible for next step
  }
}

// ---------------------------------------------------------------------------
// Head GEMM: partials[g][b][h] = seq[b, g-chunk] @ w_out[g-chunk, h]
// ---------------------------------------------------------------------------
__global__ __launch_bounds__(256, 1) void head_kernel(
    const uint16_t* __restrict__ seq, const float* __restrict__ w_out,
    float* __restrict__ partials)
{
  const int g    = blockIdx.x;
  const int tid  = threadIdx.x;
  const int lane = tid & 63;
  const int wv   = tid >> 6;

  f32x4 acc[4][4];
  #pragma unroll
  for (int i = 0; i < 4; ++i)
    #pragma unroll
    for (int c = 0; c < 4; ++c) acc[i][c] = (f32x4){0.f, 0.f, 0.f, 0.f};

  for (int ks = 0; ks < 64; ++ks) {
    const int krow = g * 2048 + ks * 32 + (lane >> 4) * 8;
    short8 bf[4];
    #pragma unroll
    for (int c = 0; c < 4; ++c) {
      short8 v;
      #pragma unroll
      for (int j = 0; j < 8; ++j)
        v[j] = (short)f2bf(w_out[(size_t)(krow + j) * H_ + c * 16 + (lane & 15)]);
      bf[c] = v;
    }
    #pragma unroll
    for (int i = 0; i < 4; ++i) {
      const int b = (wv * 4 + i) * 16 + (lane & 15);
      short8 a = *(const short8*)(seq + (size_t)b * (T_ * U_) + krow);
      #pragma unroll
      for (int c = 0; c < 4; ++c)
        acc[i][c] = __builtin_amdgcn_mfma_f32_16x16x32_bf16(a, bf[c], acc[i][c], 0, 0, 0);
    }
  }
  #pragma unroll
  for (int i = 0; i < 4; ++i)
    #pragma unroll
    for (int c = 0; c < 4; ++c)
      #pragma unroll
      for (int r = 0; r < 4; ++r) {
        const int b = wv * 64 + i * 16 + (lane >> 4) * 4 + r;
        partials[((size_t)g * B_ + b) * H_ + c * 16 + (lane & 15)] = acc[i][c][r];
      }
}

__global__ void reduce_kernel(const float* __restrict__ partials,
                              const float* __restrict__ b_out,
                              float* __restrict__ out)
{
  const int i = blockIdx.x * 256 + threadIdx.x;   // b*64 + h
  float s = b_out[i & (H_ - 1)];
  #pragma unroll 8
  for (int g = 0; g < 64; ++g) s += partials[(size_t)g * (B_ * H_) + i];
  out[i] = s;
}

// ---------------------------------------------------------------------------
extern "C" void kernel_launch(void* const* d_in, const int* in_sizes, int n_in,
                              void* d_out, int out_size, void* d_ws, size_t ws_size,
                              hipStream_t stream) {
  (void)in_sizes; (void)n_in; (void)out_size; (void)ws_size;
  const float* x     = (const float*)d_in[0];
  const float* kern  = (const float*)d_in[1];
  const float* rker  = (const float*)d_in[2];
  const float* bias  = (const float*)d_in[3];
  const float* w_out = (const float*)d_in[4];
  const float* b_out = (const float*)d_in[5];
  float* out = (float*)d_out;

  char* ws = (char*)d_ws;
  const size_t seq_bytes  = (size_t)B_ * T_ * U_ * 2;            // 64 MB
  const size_t hbuf_bytes = (size_t)32 * 2048 * 8;               // 512 KB tagged
  uint16_t* seq      = (uint16_t*)ws;
  ull*      hbuf     = (ull*)(ws + seq_bytes);
  float*    partials = (float*)(ws + seq_bytes + hbuf_bytes);    // 4 MB

  // per-launch re-init: stale tags from a previous graph replay would false-
  // match (tags cycle 1..512) -> zero the tagged buffer every launch.
  hipMemsetAsync(hbuf, 0, hbuf_bytes, stream);

  lstm_kernel<<<32, 512, 0, stream>>>(x, kern, rker, bias, seq, hbuf);
  head_kernel<<<64, 256, 0, stream>>>(seq, w_out, partials);
  reduce_kernel<<<64, 256, 0, stream>>>(partials, b_out, out);
}